// Round 8
// baseline (54.600 us; speedup 1.0000x reference)
//
#include <hip/hip_runtime.h>
#include <hip/hip_bf16.h>
#include <stdint.h>

// Locally-connected layer: X[128,32,32,64] f32, filters[900,576,64] f32
// -> out[128,30,30,64] f32.  900 per-location GEMMs: M=128 x N=64 x K=576.
// One WG per location, 512 threads = 8 waves; wave owns 16 batch x 64 fout.
// R8: K restructured into 3 MEGA-STEPS of 192 (one per filter row di; k is
// (fh,fw,fin)-flattened so each mega-step's filter slab is contiguous 48KB).
// - B: LDS tile [64 f][192 k] bf16, 24KB x 2 (dbuf), reg-staged transposed,
//   6 float4/thread in flight (3x deeper than R2-R7).
// - A: direct per-lane global loads (12 float4/mega-step), issued BEFORE
//   B(t+1) so A's vmcnt wait never drains the B prefetch queue (in-order).
// - 3 lgkm-only barriers total (was 9): R2-R7 post-mortem showed per-step
//   fixed overhead (~10.7K cy/step vs ~400 cy work) was the wall, invariant
//   under occupancy/ILP/vmcnt scheduling changes.

typedef __attribute__((ext_vector_type(4))) float  f32x4;
typedef __attribute__((ext_vector_type(8))) short  short8;

// Swizzled byte address in a [64][384B] B tile: 16B chunk index XOR'd with
// row bits, confined to each 8-chunk block (chunk = 0..23 stays 0..23).
// Verified spread: staging b32 writes 2-way (free), b128 frag reads uniform
// 8 lanes per 16B slot (= the 1KB/wave floor).
__device__ __forceinline__ uint32_t swzB(uint32_t row, uint32_t inrow) {
    uint32_t chunk = inrow >> 4;
    uint32_t s = (chunk & ~7u) | ((chunk ^ row ^ (row >> 3)) & 7u);
    return row * 384u + (s << 4) + (inrow & 15u);
}

__device__ __forceinline__ uint16_t f2bf_u(float x) {
    __hip_bfloat16 h = __float2bfloat16(x);
    uint16_t r;
    __builtin_memcpy(&r, &h, 2);
    return r;
}
__device__ __forceinline__ short f2bf(float x) { return (short)f2bf_u(x); }
__device__ __forceinline__ uint32_t pack2bf(float lo, float hi) {
    return (uint32_t)f2bf_u(lo) | ((uint32_t)f2bf_u(hi) << 16);
}

// Barrier that does NOT drain vmcnt (own LDS ops drained; global loads fly).
#define BARRIER_KEEP_VMEM()                                   \
    do {                                                      \
        asm volatile("s_waitcnt lgkmcnt(0)" ::: "memory");    \
        __builtin_amdgcn_s_barrier();                         \
    } while (0)

__global__ __launch_bounds__(512)
void lc_mfma_kernel(const float* __restrict__ X,
                    const float* __restrict__ Fl,
                    float* __restrict__ Out) {
    __shared__ __align__(16) unsigned char lds[2][24576];
    // each buffer: B tile, 64 rows (fout) x 192 bf16 (k of this mega-step)

    // Bijective XCD-chunked swizzle: 8 XCDs, nwg=900 -> q=112, r=4.
    const int orig = blockIdx.x;
    const int xcd  = orig & 7;
    const int idx  = orig >> 3;
    const int l    = (xcd < 4 ? xcd * 113 : 452 + (xcd - 4) * 112) + idx;

    const int oi = l / 30;
    const int oj = l % 30;
    const int tid  = threadIdx.x;
    const int lane = tid & 63;
    const int wave = tid >> 6;          // 0..7, owns batch rows wave*16..+15

    f32x4 acc[4];
#pragma unroll
    for (int n = 0; n < 4; ++n)
        acc[n] = f32x4{0.f, 0.f, 0.f, 0.f};

    // B staging: thread covers f = fq*4..+3, k rows {2kp,2kp+1}+64j, j=0..2
    const int fq = tid & 15;
    const int kp = tid >> 4;            // 0..31
    const float* Fb = Fl + (size_t)l * (576 * 64);

    // A direct-load addressing: lane's batch row + fin sub-offset
    const int arow = wave * 16 + (lane & 15);
    const int lg   = lane >> 4;          // 0..3 lane group
    const int lg8  = lg * 8;
    const float* Abase = X + (size_t)arow * (32 * 32 * 64) + lg8;

    const int rsel = lane & 15;

    float4 bv[6];   // B prefetch (6 k-rows x 4 f)
    float4 av[12];  // A regs for one mega-step (3 dj x 2 fin-halves x 2)

#define ISSUE_B(T)                                                              \
    do {                                                                        \
        const float* b_ = Fb + (size_t)((T) * 192 + 2 * kp) * 64 + fq * 4;      \
        bv[0] = *(const float4*)(b_);        bv[1] = *(const float4*)(b_ + 64); \
        bv[2] = *(const float4*)(b_ + 4096); bv[3] = *(const float4*)(b_ + 4160); \
        bv[4] = *(const float4*)(b_ + 8192); bv[5] = *(const float4*)(b_ + 8256); \
    } while (0)

#define WRITE_B(BUF)                                                            \
    do {                                                                        \
        unsigned char* L_ = lds[BUF];                                           \
        _Pragma("unroll")                                                       \
        for (int j = 0; j < 3; ++j) {                                           \
            const uint32_t inrow = (uint32_t)(4 * kp + 128 * j);                \
            *(uint32_t*)&L_[swzB(fq*4 + 0, inrow)] = pack2bf(bv[2*j].x, bv[2*j+1].x); \
            *(uint32_t*)&L_[swzB(fq*4 + 1, inrow)] = pack2bf(bv[2*j].y, bv[2*j+1].y); \
            *(uint32_t*)&L_[swzB(fq*4 + 2, inrow)] = pack2bf(bv[2*j].z, bv[2*j+1].z); \
            *(uint32_t*)&L_[swzB(fq*4 + 3, inrow)] = pack2bf(bv[2*j].w, bv[2*j+1].w); \
        }                                                                       \
    } while (0)

#define ISSUE_A(T)                                                              \
    do {                                                                        \
        _Pragma("unroll")                                                       \
        for (int dj = 0; dj < 3; ++dj) {                                        \
            const float* p_ = Abase + (((oi + (T)) * 32 + (oj + dj)) * 64);     \
            av[dj*4 + 0] = *(const float4*)(p_);                                \
            av[dj*4 + 1] = *(const float4*)(p_ + 4);                            \
            av[dj*4 + 2] = *(const float4*)(p_ + 32);                           \
            av[dj*4 + 3] = *(const float4*)(p_ + 36);                           \
        }                                                                       \
    } while (0)

    // prologue: stage mega-step 0's B into buffer 0
    ISSUE_B(0);
    WRITE_B(0);

#pragma unroll 1
    for (int t = 0; t < 3; ++t) {
        // A first (so compute's A-wait leaves B(t+1) in flight: vmcnt is
        // in-order and A's 12 loads are older), then next B slab.
        ISSUE_A(t);
        if (t < 2) ISSUE_B(t + 1);

        BARRIER_KEEP_VMEM();  // lds[t&1] B-writes (prev iter / prologue) visible

        const unsigned char* L = lds[t & 1];
#pragma unroll
        for (int kk = 0; kk < 6; ++kk) {
            const int dj = kk >> 1, h = kk & 1;
            short8 af;
            const float4 u0 = av[dj*4 + h*2], u1 = av[dj*4 + h*2 + 1];
            af[0]=f2bf(u0.x); af[1]=f2bf(u0.y); af[2]=f2bf(u0.z); af[3]=f2bf(u0.w);
            af[4]=f2bf(u1.x); af[5]=f2bf(u1.y); af[6]=f2bf(u1.z); af[7]=f2bf(u1.w);
            const uint32_t inrow = (uint32_t)(kk * 64 + lg * 16);
            const short8 b0 = *(const short8*)&L[swzB(     rsel, inrow)];
            const short8 b1 = *(const short8*)&L[swzB(16 + rsel, inrow)];
            const short8 b2 = *(const short8*)&L[swzB(32 + rsel, inrow)];
            const short8 b3 = *(const short8*)&L[swzB(48 + rsel, inrow)];
            acc[0] = __builtin_amdgcn_mfma_f32_16x16x32_bf16(af, b0, acc[0], 0, 0, 0);
            acc[1] = __builtin_amdgcn_mfma_f32_16x16x32_bf16(af, b1, acc[1], 0, 0, 0);
            acc[2] = __builtin_amdgcn_mfma_f32_16x16x32_bf16(af, b2, acc[2], 0, 0, 0);
            acc[3] = __builtin_amdgcn_mfma_f32_16x16x32_bf16(af, b3, acc[3], 0, 0, 0);
        }

        // write mega-step t+1's B into the other buffer; its previous readers
        // all passed the barrier above. One barrier per mega-step total.
        if (t < 2) WRITE_B((t + 1) & 1);
    }

    // epilogue: D layout col=lane&15, row=(lane>>4)*4+reg (m89-verified)
    const int col = lane & 15;
    const int rb  = (lane >> 4) * 4;
#pragma unroll
    for (int n = 0; n < 4; ++n)
#pragma unroll
        for (int i = 0; i < 4; ++i) {
            const int row = wave * 16 + rb + i;   // batch index
            const int f   = n * 16 + col;         // fout index
            Out[((size_t)row * 900 + l) * 64 + f] = acc[n][i];
        }
}

extern "C" void kernel_launch(void* const* d_in, const int* in_sizes, int n_in,
                              void* d_out, int out_size, void* d_ws, size_t ws_size,
                              hipStream_t stream) {
    const float* X  = (const float*)d_in[0];   // [128,32,32,64]
    const float* Fl = (const float*)d_in[1];   // [900,576,64]
    float* Out = (float*)d_out;                // [128,30,30,64]
    lc_mfma_kernel<<<dim3(900), dim3(512), 0, stream>>>(X, Fl, Out);
}

// Round 9
// 54.451 us; speedup vs baseline: 1.0027x; 1.0027x over previous
//
#include <hip/hip_runtime.h>
#include <hip/hip_bf16.h>
#include <stdint.h>

// Locally-connected layer: X[128,32,32,64] f32, filters[900,576,64] f32
// -> out[128,30,30,64] f32.  900 per-location GEMMs: M=128 x N=64 x K=576.
// One WG per location, 512 threads = 8 waves; wave owns 16 batch x 64 fout.
// R9: fully decoupled 2-phase structure.
//  Phase 1 (stream): entire 576x64 filter slab (147KB f32) loaded in one
//    ring-3 pipelined burst -> bf16 transposed swizzled LDS tile [64f][576k]
//    (73.7KB, single buffer). Max MLP, memory unit continuously fed.
//  Phase 2 (free-run): ONE barrier, then 18 K=32 steps of pure compute with
//    NO further synchronization. A fragments loaded direct from global
//    (X is L2/L3-hot; ring-3 lookahead); B frags from LDS; 4 MFMA/step.
//  Rationale: R2-R8 showed the lockstep load->drain->barrier->compute convoy
//  is invariant at ~40.5us under occupancy/ILP/vmcnt/barrier-count changes;
//  all pipes <15% busy. Decoupling lets 16 resident waves/CU occupy memory,
//  LDS, and MFMA pipes at staggered phases.

typedef __attribute__((ext_vector_type(4))) float  f32x4;
typedef __attribute__((ext_vector_type(8))) short  short8;

// Swizzled byte address in the [64 f][1152 B] B tile: XOR 16B-chunk index
// (low 3 bits) with row bits. Staging b32 writes: 2-way spread (free);
// b128 frag reads: uniform 8 lanes per 16B slot (= 1KB/wave floor).
__device__ __forceinline__ uint32_t swzB(uint32_t row, uint32_t inrow) {
    uint32_t chunk = inrow >> 4;
    uint32_t s = (chunk & ~7u) | ((chunk ^ row ^ (row >> 3)) & 7u);
    return row * 1152u + (s << 4) + (inrow & 15u);
}

__device__ __forceinline__ uint16_t f2bf_u(float x) {
    __hip_bfloat16 h = __float2bfloat16(x);
    uint16_t r;
    __builtin_memcpy(&r, &h, 2);
    return r;
}
__device__ __forceinline__ short f2bf(float x) { return (short)f2bf_u(x); }
__device__ __forceinline__ uint32_t pack2bf(float lo, float hi) {
    return (uint32_t)f2bf_u(lo) | ((uint32_t)f2bf_u(hi) << 16);
}

// Barrier that waits only LDS ops (lgkmcnt); in-flight global loads cross.
#define BARRIER_KEEP_VMEM()                                   \
    do {                                                      \
        asm volatile("s_waitcnt lgkmcnt(0)" ::: "memory");    \
        __builtin_amdgcn_s_barrier();                         \
    } while (0)

__global__ __launch_bounds__(512)
void lc_mfma_kernel(const float* __restrict__ X,
                    const float* __restrict__ Fl,
                    float* __restrict__ Out) {
    __shared__ __align__(16) unsigned char lds[73728];  // B tile [64][1152B]

    // Bijective XCD-chunked swizzle: 8 XCDs, nwg=900 -> q=112, r=4.
    const int orig = blockIdx.x;
    const int xcd  = orig & 7;
    const int idx  = orig >> 3;
    const int l    = (xcd < 4 ? xcd * 113 : 452 + (xcd - 4) * 112) + idx;

    const int oi = l / 30;
    const int oj = l % 30;
    const int tid  = threadIdx.x;
    const int lane = tid & 63;
    const int wave = tid >> 6;          // 0..7, owns batch rows wave*16..+15

    f32x4 acc[4];
#pragma unroll
    for (int n = 0; n < 4; ++n)
        acc[n] = f32x4{0.f, 0.f, 0.f, 0.f};

    // B staging: thread covers f = fq*4..+3, k rows {2kp, 2kp+1} per 64k-slab
    const int fq = tid & 15;
    const int kp = tid >> 4;            // 0..31
    const float* Fb = Fl + (size_t)l * (576 * 64);

    // A direct-load addressing: lane's batch row + fin-group
    const int rsel = lane & 15;
    const int lg   = lane >> 4;         // 0..3
    const int arow = wave * 16 + rsel;
    const float* Abase = X + (size_t)arow * (32 * 32 * 64) + lg * 8;

    // ---------------- Phase 1: stream B (9 slabs, ring of 3) ----------------
    float4 b0[2], b1[2], b2[2];

#define ISSUE_B(S, BV)                                                          \
    do {                                                                        \
        const float* p_ = Fb + (size_t)((S) * 64 + 2 * kp) * 64 + fq * 4;       \
        BV[0] = *(const float4*)(p_);                                           \
        BV[1] = *(const float4*)(p_ + 64);                                      \
    } while (0)

#define WRITE_B(S, BV)                                                          \
    do {                                                                        \
        const uint32_t inrow = (uint32_t)((S) * 128 + kp * 4);                  \
        *(uint32_t*)&lds[swzB(fq*4 + 0, inrow)] = pack2bf(BV[0].x, BV[1].x);    \
        *(uint32_t*)&lds[swzB(fq*4 + 1, inrow)] = pack2bf(BV[0].y, BV[1].y);    \
        *(uint32_t*)&lds[swzB(fq*4 + 2, inrow)] = pack2bf(BV[0].z, BV[1].z);    \
        *(uint32_t*)&lds[swzB(fq*4 + 3, inrow)] = pack2bf(BV[0].w, BV[1].w);    \
    } while (0)

    ISSUE_B(0, b0); ISSUE_B(1, b1); ISSUE_B(2, b2);
#pragma unroll
    for (int g = 0; g < 3; ++g) {
        WRITE_B(g*3 + 0, b0); if (g < 2) ISSUE_B(g*3 + 3, b0);
        WRITE_B(g*3 + 1, b1); if (g < 2) ISSUE_B(g*3 + 4, b1);
        WRITE_B(g*3 + 2, b2); if (g < 2) ISSUE_B(g*3 + 5, b2);
    }

    // ---------------- Phase 2: one barrier, then free-run compute -----------
    float4 a0[2], a1[2], a2[2];

#define ISSUE_A(KK, AV)                                                         \
    do {                                                                        \
        const int h_ = oi + (KK) / 6;                                           \
        const int w_ = oj + (((KK) % 6) >> 1);                                  \
        const float* p_ = Abase + ((h_ * 32 + w_) * 64 + ((KK) & 1) * 32);      \
        AV[0] = *(const float4*)(p_);                                           \
        AV[1] = *(const float4*)(p_ + 4);                                       \
    } while (0)

#define COMPUTE(KK, AV)                                                         \
    do {                                                                        \
        short8 af;                                                              \
        af[0]=f2bf(AV[0].x); af[1]=f2bf(AV[0].y);                               \
        af[2]=f2bf(AV[0].z); af[3]=f2bf(AV[0].w);                               \
        af[4]=f2bf(AV[1].x); af[5]=f2bf(AV[1].y);                               \
        af[6]=f2bf(AV[1].z); af[7]=f2bf(AV[1].w);                               \
        const uint32_t inrow = (uint32_t)((KK) * 64 + lg * 16);                 \
        const short8 f0 = *(const short8*)&lds[swzB(     rsel, inrow)];         \
        const short8 f1 = *(const short8*)&lds[swzB(16 + rsel, inrow)];         \
        const short8 f2 = *(const short8*)&lds[swzB(32 + rsel, inrow)];         \
        const short8 f3 = *(const short8*)&lds[swzB(48 + rsel, inrow)];         \
        acc[0] = __builtin_amdgcn_mfma_f32_16x16x32_bf16(af, f0, acc[0], 0, 0, 0); \
        acc[1] = __builtin_amdgcn_mfma_f32_16x16x32_bf16(af, f1, acc[1], 0, 0, 0); \
        acc[2] = __builtin_amdgcn_mfma_f32_16x16x32_bf16(af, f2, acc[2], 0, 0, 0); \
        acc[3] = __builtin_amdgcn_mfma_f32_16x16x32_bf16(af, f3, acc[3], 0, 0, 0); \
    } while (0)

    // prefetch A for kk = 0,1,2 before the barrier (they cross it in flight)
    ISSUE_A(0, a0); ISSUE_A(1, a1); ISSUE_A(2, a2);

    BARRIER_KEEP_VMEM();   // B tile visible; no further barriers

#pragma unroll
    for (int g = 0; g < 6; ++g) {
        COMPUTE(g*3 + 0, a0); if (g < 5) ISSUE_A(g*3 + 3, a0);
        COMPUTE(g*3 + 1, a1); if (g < 5) ISSUE_A(g*3 + 4, a1);
        COMPUTE(g*3 + 2, a2); if (g < 5) ISSUE_A(g*3 + 5, a2);
    }

    // ---------------- epilogue: D layout col=lane&15, row=(lane>>4)*4+reg ---
    const int col = lane & 15;
    const int rb  = (lane >> 4) * 4;
#pragma unroll
    for (int n = 0; n < 4; ++n)
#pragma unroll
        for (int i = 0; i < 4; ++i) {
            const int row = wave * 16 + rb + i;   // batch index
            const int f   = n * 16 + col;         // fout index
            Out[((size_t)row * 900 + l) * 64 + f] = acc[n][i];
        }
}

extern "C" void kernel_launch(void* const* d_in, const int* in_sizes, int n_in,
                              void* d_out, int out_size, void* d_ws, size_t ws_size,
                              hipStream_t stream) {
    const float* X  = (const float*)d_in[0];   // [128,32,32,64]
    const float* Fl = (const float*)d_in[1];   // [900,576,64]
    float* Out = (float*)d_out;                // [128,30,30,64]
    lc_mfma_kernel<<<dim3(900), dim3(512), 0, stream>>>(X, Fl, Out);
}

// Round 10
// 50.478 us; speedup vs baseline: 1.0817x; 1.0787x over previous
//
#include <hip/hip_runtime.h>
#include <hip/hip_bf16.h>
#include <stdint.h>

// Locally-connected layer: X[128,32,32,64] f32, filters[900,576,64] f32
// -> out[128,30,30,64] f32.  900 per-location GEMMs: M=128 x N=64 x K=576.
// R10: 450 WGs x 2 ADJACENT locations per WG (tail elimination).
//   Makespan model from R2-R9: 900 WGs at 3 WG/CU = 768-WG batch + 132-WG
//   tail batch -> wall = 2 x T_WG with the tail running the machine at 17%.
//   450 WGs < 768 co-resident slots = ONE batch, no tail. Inner pipeline is
//   the proven R5 structure (512 thr = 8 waves, A[128x64]+B[64x64] bf16
//   dbuf LDS 48KB, 1-deep reg prefetch, one lgkm-only barrier per K-step),
//   run 18 steps with buffer parity continuous across the location seam so
//   the filter stream never pauses. Pair (2p,2p+1) never straddles a row
//   (30 even): contiguous 294KB filter stream, 2/3-overlapping X windows.

typedef __attribute__((ext_vector_type(4))) float  f32x4;
typedef __attribute__((ext_vector_type(8))) short  short8;

#define BOFF 16384  // byte offset of B tile inside one LDS buffer

// XOR swizzle on 16B chunks within a 128B row.
__device__ __forceinline__ uint32_t swz_addr(uint32_t row, uint32_t inrow) {
    uint32_t chunk = inrow >> 4;
    uint32_t rem   = inrow & 15u;
    return row * 128u + (((chunk ^ row ^ (row >> 3)) & 7u) << 4) + rem;
}

__device__ __forceinline__ uint16_t f2bf_u(float x) {
    __hip_bfloat16 h = __float2bfloat16(x);
    uint16_t r;
    __builtin_memcpy(&r, &h, 2);
    return r;
}
__device__ __forceinline__ short f2bf(float x) { return (short)f2bf_u(x); }
__device__ __forceinline__ uint32_t pack2bf(float lo, float hi) {
    return (uint32_t)f2bf_u(lo) | ((uint32_t)f2bf_u(hi) << 16);
}

// Barrier that waits only LDS ops; in-flight global loads cross it.
#define BARRIER_KEEP_VMEM()                                   \
    do {                                                      \
        asm volatile("s_waitcnt lgkmcnt(0)" ::: "memory");    \
        __builtin_amdgcn_s_barrier();                         \
    } while (0)

__global__ __launch_bounds__(512)
void lc_mfma_kernel(const float* __restrict__ X,
                    const float* __restrict__ Fl,
                    float* __restrict__ Out) {
    __shared__ __align__(16) unsigned char lds[2][24576];
    // each buffer: [0,16384) A tile 128rows x 64 bf16 (swizzled)
    //              [16384,24576) B tile 64rows(fout) x 64 bf16 (swizzled)

    // Bijective XCD-chunked swizzle over 450 pairs: q=56, r=2.
    const int orig = blockIdx.x;
    const int xcd  = orig & 7;
    const int idx  = orig >> 3;
    const int pair = (xcd < 2 ? xcd * 57 : 114 + (xcd - 2) * 56) + idx;
    const int l0   = pair * 2;          // this WG handles l0 and l0+1

    const int oi  = l0 / 30;
    const int oj0 = l0 % 30;            // l0+1 is (oi, oj0+1): never wraps
    const int tid  = threadIdx.x;
    const int lane = tid & 63;
    const int wave = tid >> 6;          // 0..7, owns batch rows wave*16..+15

    f32x4 acc[4];
#pragma unroll
    for (int n = 0; n < 4; ++n)
        acc[n] = f32x4{0.f, 0.f, 0.f, 0.f};

    // A staging: thread covers row ar (0..127), fin quarter aq*16..+15
    const int ar = tid >> 2;
    const int aq = tid & 3;
    // B staging (all 512 threads): f block fq*4..+3, k rows {2kp,2kp+1}
    const int fq = tid & 15;
    const int kp = tid >> 4;            // 0..31

    const float* Fb0 = Fl + (size_t)l0 * (576 * 64);

    float4 av[4];  // prefetched A regs (1 row-quarter, 16 fin)
    float4 bv[2];  // prefetched B regs (2 k-rows x 4 f)

    // GS = global step 0..17: half = GS>=9 (location l0+half), s = GS-9*half
#define ISSUE_LOADS(GS)                                                         \
    do {                                                                        \
        const int half_ = (GS) >= 9 ? 1 : 0;                                    \
        const int s_  = (GS) - half_ * 9;                                       \
        const int di_ = s_ / 3, dj_ = s_ % 3;                                   \
        const int h_ = oi + di_, w_ = oj0 + half_ + dj_;                        \
        const float* a_ = X + (((size_t)ar * 32 + h_) * 32 + w_) * 64 + aq*16;  \
        av[0] = ((const float4*)a_)[0]; av[1] = ((const float4*)a_)[1];         \
        av[2] = ((const float4*)a_)[2]; av[3] = ((const float4*)a_)[3];         \
        const float* b_ = Fb0 + (size_t)half_ * (576*64)                        \
                              + (size_t)s_ * 4096 + (size_t)(kp*2) * 64 + fq*4; \
        bv[0] = *(const float4*)(b_);                                           \
        bv[1] = *(const float4*)(b_ + 64);                                      \
    } while (0)

#define WRITE_LDS(BUF)                                                          \
    do {                                                                        \
        unsigned char* L_ = lds[BUF];                                           \
        short8 p0, p1;                                                          \
        p0[0]=f2bf(av[0].x); p0[1]=f2bf(av[0].y); p0[2]=f2bf(av[0].z); p0[3]=f2bf(av[0].w); \
        p0[4]=f2bf(av[1].x); p0[5]=f2bf(av[1].y); p0[6]=f2bf(av[1].z); p0[7]=f2bf(av[1].w); \
        p1[0]=f2bf(av[2].x); p1[1]=f2bf(av[2].y); p1[2]=f2bf(av[2].z); p1[3]=f2bf(av[2].w); \
        p1[4]=f2bf(av[3].x); p1[5]=f2bf(av[3].y); p1[6]=f2bf(av[3].z); p1[7]=f2bf(av[3].w); \
        *(short8*)&L_[swz_addr(ar, aq*32 + 0 )] = p0;                           \
        *(short8*)&L_[swz_addr(ar, aq*32 + 16)] = p1;                           \
        *(uint32_t*)&L_[BOFF + swz_addr(fq*4 + 0, kp*4)] = pack2bf(bv[0].x, bv[1].x); \
        *(uint32_t*)&L_[BOFF + swz_addr(fq*4 + 1, kp*4)] = pack2bf(bv[0].y, bv[1].y); \
        *(uint32_t*)&L_[BOFF + swz_addr(fq*4 + 2, kp*4)] = pack2bf(bv[0].z, bv[1].z); \
        *(uint32_t*)&L_[BOFF + swz_addr(fq*4 + 3, kp*4)] = pack2bf(bv[0].w, bv[1].w); \
    } while (0)

#define EPILOGUE(LCUR)                                                          \
    do {                                                                        \
        const int col = lane & 15;                                              \
        const int rb  = (lane >> 4) * 4;                                        \
        _Pragma("unroll")                                                       \
        for (int n = 0; n < 4; ++n)                                             \
            _Pragma("unroll")                                                   \
            for (int i = 0; i < 4; ++i) {                                       \
                const int row = wave * 16 + rb + i;                             \
                const int f   = n * 16 + col;                                   \
                Out[((size_t)row * 900 + (LCUR)) * 64 + f] = acc[n][i];         \
                acc[n][i] = 0.f;                                                \
            }                                                                   \
    } while (0)

    // prologue: stage step 0 (location l0) into buffer 0
    ISSUE_LOADS(0);
    WRITE_LDS(0);

    const int mb   = wave * 16;
    const int rsel = lane & 15;
    const int ksel = (lane >> 4) * 16;

#pragma unroll 1
    for (int gs = 0; gs < 18; ++gs) {
        // issue next global step's loads; they stay in flight across the
        // barrier; vmcnt wait lands at WRITE_LDS after this step's compute.
        if (gs < 17) ISSUE_LOADS(gs + 1);

        BARRIER_KEEP_VMEM();  // lds[gs&1] writes (prev iter / prologue) visible

        const unsigned char* L = lds[gs & 1];
#pragma unroll
        for (int kk = 0; kk < 2; ++kk) {
            const uint32_t inrow = (uint32_t)(kk * 64 + ksel);
            const short8 a0 = *(const short8*)&L[swz_addr(mb + rsel, inrow)];
            const short8 b0 = *(const short8*)&L[BOFF + swz_addr(     rsel, inrow)];
            const short8 b1 = *(const short8*)&L[BOFF + swz_addr(16 + rsel, inrow)];
            const short8 b2 = *(const short8*)&L[BOFF + swz_addr(32 + rsel, inrow)];
            const short8 b3 = *(const short8*)&L[BOFF + swz_addr(48 + rsel, inrow)];
            acc[0] = __builtin_amdgcn_mfma_f32_16x16x32_bf16(a0, b0, acc[0], 0, 0, 0);
            acc[1] = __builtin_amdgcn_mfma_f32_16x16x32_bf16(a0, b1, acc[1], 0, 0, 0);
            acc[2] = __builtin_amdgcn_mfma_f32_16x16x32_bf16(a0, b2, acc[2], 0, 0, 0);
            acc[3] = __builtin_amdgcn_mfma_f32_16x16x32_bf16(a0, b3, acc[3], 0, 0, 0);
        }

        // location seam: after step 8's compute, flush loc l0's output while
        // loc l0+1's step-0 loads are in flight, then reset the accumulator.
        if (gs == 8) EPILOGUE(l0);

        // write next step into the other buffer; its previous readers all
        // passed the barrier above. One barrier per step total.
        if (gs < 17) WRITE_LDS((gs + 1) & 1);
    }

    EPILOGUE(l0 + 1);
}

extern "C" void kernel_launch(void* const* d_in, const int* in_sizes, int n_in,
                              void* d_out, int out_size, void* d_ws, size_t ws_size,
                              hipStream_t stream) {
    const float* X  = (const float*)d_in[0];   // [128,32,32,64]
    const float* Fl = (const float*)d_in[1];   // [900,576,64]
    float* Out = (float*)d_out;                // [128,30,30,64]
    lc_mfma_kernel<<<dim3(450), dim3(512), 0, stream>>>(X, Fl, Out);
}

// Round 11
// 43.566 us; speedup vs baseline: 1.2533x; 1.1587x over previous
//
#include <hip/hip_runtime.h>
#include <hip/hip_bf16.h>
#include <stdint.h>

// Locally-connected layer: X[128,32,32,64] f32, filters[900,576,64] f32
// -> out[128,30,30,64] f32.  900 per-location GEMMs: M=128 x N=64 x K=576.
// One WG per location, 512 threads = 8 waves; wave owns 16 batch x 64 fout.
// R11: DMA-pipelined staging (guide Common-mistake #1: global_load_lds was
// never used in R1-R10; all reg-staged variants pinned at 40.5us).
//  - A tile (X, 32KB/step): global_load_lds f32 -> LDS, dbuf, issued 1 step
//    ahead. Zero staging VGPRs/VALU. Source-XOR chunk swizzle (LDS linear,
//    global source permuted; read side applies the same XOR) -> 2-way banks.
//  - B (filters, the HBM stream): R5's reg-staged bf16-transposed swizzled
//    LDS path, 2-deep register sets -> issue->consume window > HBM latency.
//  - Counted vmcnt (never 0 mid-loop): top-of-iter s_waitcnt vmcnt(2)
//    drains A(s) only, leaves B(s+1) in flight. lgkm-only barrier.
//  - LDS 2x32KB + 2x8KB = 80KB -> exactly 2 WG/CU (16 waves/CU).

typedef __attribute__((ext_vector_type(4))) float  f32x4;
typedef __attribute__((ext_vector_type(8))) short  short8;

typedef __attribute__((address_space(1))) void as1_void;
typedef __attribute__((address_space(3))) void as3_void;

__device__ __forceinline__ void gload16(const void* g, void* l) {
    __builtin_amdgcn_global_load_lds((as1_void*)g, (as3_void*)l, 16, 0, 0);
}

// B-tile XOR swizzle on 16B chunks within a 128B row (proven R5 path).
__device__ __forceinline__ uint32_t swz_addr(uint32_t row, uint32_t inrow) {
    uint32_t chunk = inrow >> 4;
    uint32_t rem   = inrow & 15u;
    return row * 128u + (((chunk ^ row ^ (row >> 3)) & 7u) << 4) + rem;
}

__device__ __forceinline__ uint16_t f2bf_u(float x) {
    __hip_bfloat16 h = __float2bfloat16(x);
    uint16_t r;
    __builtin_memcpy(&r, &h, 2);
    return r;
}
__device__ __forceinline__ short f2bf(float x) { return (short)f2bf_u(x); }
__device__ __forceinline__ uint32_t pack2bf(float lo, float hi) {
    return (uint32_t)f2bf_u(lo) | ((uint32_t)f2bf_u(hi) << 16);
}

__global__ __launch_bounds__(512)
void lc_mfma_kernel(const float* __restrict__ X,
                    const float* __restrict__ Fl,
                    float* __restrict__ Out) {
    // [0,65536): A dbuf, 2 x [128 rows][64 fin] f32 linear (source-swizzled)
    // [65536,81920): B dbuf, 2 x [64 f][64 k] bf16 swizzled
    __shared__ __align__(16) unsigned char lds[81920];

    // Bijective XCD-chunked swizzle: 8 XCDs, nwg=900 -> q=112, r=4.
    const int orig = blockIdx.x;
    const int xcd  = orig & 7;
    const int idx  = orig >> 3;
    const int l    = (xcd < 4 ? xcd * 113 : 452 + (xcd - 4) * 112) + idx;

    const int oi = l / 30;
    const int oj = l % 30;
    const int tid  = threadIdx.x;
    const int lane = tid & 63;
    const int wave = tid >> 6;          // 0..7, owns batch rows wave*16..+15

    f32x4 acc[4];
#pragma unroll
    for (int n = 0; n < 4; ++n)
        acc[n] = f32x4{0.f, 0.f, 0.f, 0.f};

    // DMA lane decomposition: each wave-instr moves 4 rows x 256B = 1KB
    const int lrow = lane >> 4;         // 0..3 row within instr
    const int lchk = lane & 15;         // 16B chunk within row

    // B staging (all 512 threads): f block fq*4..+3, k rows {2kp,2kp+1}
    const int fq = tid & 15;
    const int kp = tid >> 4;            // 0..31
    const float* Fb = Fl + (size_t)l * (576 * 64);

    const char* Xb = (const char*)X;

    // MFMA fragment selectors
    const int rsel = lane & 15;
    const int kg   = lane >> 4;         // 0..3
    const int mb   = wave * 16;
    const int ksel = kg * 16;           // byte offset of lane's 8 bf16 in B row

    float4 bvA[2], bvB[2];              // 2-deep B prefetch sets

    // ---- A: global_load_lds, source-XOR swizzled, into A-buffer BUF ----
#define ISSUE_A(S, BUF)                                                         \
    do {                                                                        \
        const int h_ = oi + (S) / 3, w_ = oj + (S) % 3;                         \
        const size_t pix_ = ((size_t)(h_ * 32 + w_)) * 256;                     \
        unsigned char* ab_ = &lds[(BUF) * 32768u];                              \
        _Pragma("unroll")                                                       \
        for (int i_ = 0; i_ < 4; ++i_) {                                        \
            const int row_ = wave * 16 + i_ * 4 + lrow;                         \
            const uint32_t sc_ = (uint32_t)(lchk ^ (row_ & 15));                \
            gload16(Xb + (size_t)row_ * 262144 + pix_ + (sc_ << 4),             \
                    ab_ + (wave * 16 + i_ * 4) * 256);                          \
        }                                                                       \
    } while (0)

    // ---- B: register load (2 k-rows x 4 f) for step S ----
#define ISSUE_B(S, BV)                                                          \
    do {                                                                        \
        const float* b_ = Fb + (size_t)((S) * 64 + 2 * kp) * 64 + fq * 4;       \
        BV[0] = *(const float4*)(b_);                                           \
        BV[1] = *(const float4*)(b_ + 64);                                      \
    } while (0)

    // ---- B: convert+transpose into bf16 swizzled LDS buffer (S&1) ----
#define WRITE_B(S, BV)                                                          \
    do {                                                                        \
        unsigned char* L_ = &lds[65536u + ((S) & 1) * 8192u];                   \
        *(uint32_t*)&L_[swz_addr(fq*4 + 0, kp*4)] = pack2bf(BV[0].x, BV[1].x);  \
        *(uint32_t*)&L_[swz_addr(fq*4 + 1, kp*4)] = pack2bf(BV[0].y, BV[1].y);  \
        *(uint32_t*)&L_[swz_addr(fq*4 + 2, kp*4)] = pack2bf(BV[0].z, BV[1].z);  \
        *(uint32_t*)&L_[swz_addr(fq*4 + 3, kp*4)] = pack2bf(BV[0].w, BV[1].w);  \
    } while (0)

    // prologue: ages (oldest->youngest): B(0), A(0), B(1)
    ISSUE_B(0, bvA);
    ISSUE_A(0, 0);
    ISSUE_B(1, bvB);
    WRITE_B(0, bvA);   // compiler auto-waits B(0) regs (leaves A(0),B(1) flying)

#pragma unroll 1
    for (int s = 0; s < 9; ++s) {
        // Drain A(s) only: at loop top the outstanding set is {A(s):6, B(s+1):2}
        // (B(s+1) is younger). vmcnt(2) completes A(s); B(s+1) stays in flight.
        if (s < 8) asm volatile("s_waitcnt vmcnt(2) lgkmcnt(0)" ::: "memory");
        else       asm volatile("s_waitcnt vmcnt(0) lgkmcnt(0)" ::: "memory");
        __builtin_amdgcn_sched_barrier(0);
        __builtin_amdgcn_s_barrier();
        __builtin_amdgcn_sched_barrier(0);

        // Issue next A DMA (buffer (s+1)&1 was fully read at iter s-1; all
        // waves passed the barrier above, so overwrite is safe), then next B.
        if (s < 8) ISSUE_A(s + 1, (s + 1) & 1);
        if (s < 7) {
            if ((s & 1) == 0) ISSUE_B(s + 2, bvA);
            else              ISSUE_B(s + 2, bvB);
        }

        // ---- compute step s ----
        {
            const unsigned char* LA = &lds[(s & 1) * 32768u];
            const unsigned char* LB = &lds[65536u + (s & 1) * 8192u];
#pragma unroll
            for (int kk = 0; kk < 2; ++kk) {
                const int cf = kk * 8 + kg * 2;
                const int ar = mb + rsel;
                const int rx = ar & 15;
                const f32x4 fa0 = *(const f32x4*)&LA[(uint32_t)(ar * 256 + ((cf ^ rx) << 4))];
                const f32x4 fa1 = *(const f32x4*)&LA[(uint32_t)(ar * 256 + (((cf + 1) ^ rx) << 4))];
                short8 af;
                af[0]=f2bf(fa0[0]); af[1]=f2bf(fa0[1]); af[2]=f2bf(fa0[2]); af[3]=f2bf(fa0[3]);
                af[4]=f2bf(fa1[0]); af[5]=f2bf(fa1[1]); af[6]=f2bf(fa1[2]); af[7]=f2bf(fa1[3]);
                const uint32_t inrow = (uint32_t)(kk * 64 + ksel);
                const short8 b0 = *(const short8*)&LB[swz_addr(     rsel, inrow)];
                const short8 b1 = *(const short8*)&LB[swz_addr(16 + rsel, inrow)];
                const short8 b2 = *(const short8*)&LB[swz_addr(32 + rsel, inrow)];
                const short8 b3 = *(const short8*)&LB[swz_addr(48 + rsel, inrow)];
                acc[0] = __builtin_amdgcn_mfma_f32_16x16x32_bf16(af, b0, acc[0], 0, 0, 0);
                acc[1] = __builtin_amdgcn_mfma_f32_16x16x32_bf16(af, b1, acc[1], 0, 0, 0);
                acc[2] = __builtin_amdgcn_mfma_f32_16x16x32_bf16(af, b2, acc[2], 0, 0, 0);
                acc[3] = __builtin_amdgcn_mfma_f32_16x16x32_bf16(af, b3, acc[3], 0, 0, 0);
            }
        }

        // write B(s+1) into the other LDS half; its previous readers all
        // passed the barrier above. Compiler's auto-wait for the BV set
        // leaves the younger A(s+1)/B(s+2) loads in flight.
        if (s < 8) {
            if (((s + 1) & 1) == 0) WRITE_B(s + 1, bvA);
            else                    WRITE_B(s + 1, bvB);
        }
    }

    // epilogue: D layout col=lane&15, row=(lane>>4)*4+reg (m89-verified)
    const int col = lane & 15;
    const int rb  = (lane >> 4) * 4;
#pragma unroll
    for (int n = 0; n < 4; ++n)
#pragma unroll
        for (int i = 0; i < 4; ++i) {
            const int row = mb + rb + i;      // batch index
            const int f   = n * 16 + col;     // fout index
            Out[((size_t)row * 900 + l) * 64 + f] = acc[n][i];
        }
}

extern "C" void kernel_launch(void* const* d_in, const int* in_sizes, int n_in,
                              void* d_out, int out_size, void* d_ws, size_t ws_size,
                              hipStream_t stream) {
    const float* X  = (const float*)d_in[0];   // [128,32,32,64]
    const float* Fl = (const float*)d_in[1];   // [900,576,64]
    float* Out = (float*)d_out;                // [128,30,30,64]
    lc_mfma_kernel<<<dim3(900), dim3(512), 0, stream>>>(X, Fl, Out);
}